// Round 1
// baseline (7653.732 us; speedup 1.0000x reference)
//
#include <hip/hip_runtime.h>
#include <math.h>

// NerfMLP: S=64 samples/ray, B=4096 rays, H=256.
// One block per ray (64 points), 512 threads, fully fused MLP + volume render.
// No workspace needed.

#define SS 64
#define BB 4096
#define HH 256
#define NEAR_ 2.0f
#define FAR_ 6.0f

#define TPB 512
#define LDH 260   // h row stride in floats (260 = 4*65: keeps b128 alignment, breaks bank aliasing)
#define LDE 32    // enc row stride
#define KC 32     // K-chunk staged in LDS

struct Smem {
  float h[64 * LDH];      // activations, 66,560 B
  float enc[64 * LDE];    // positional encoding, 8,192 B
  float wst[KC * 256];    // staged weight chunk, 32,768 B
  float dist[64];
  float vdir[3];
};
// total ~107.8 KB -> 1 block/CU, 8 waves (2/SIMD)

__device__ __forceinline__ void accum_chunk(const float* __restrict__ a0,
                                            const float* __restrict__ a1,
                                            const float* __restrict__ wbase,
                                            float acc[2][16]) {
  #pragma unroll
  for (int k4 = 0; k4 < KC; k4 += 4) {
    float4 av0 = *(const float4*)(a0 + k4);
    float4 av1 = *(const float4*)(a1 + k4);
    #pragma unroll
    for (int kk = 0; kk < 4; ++kk) {
      const float* wr = wbase + (k4 + kk) * 256;
      float4 w0v = *(const float4*)(wr + 0);
      float4 w1v = *(const float4*)(wr + 4);
      float4 w2v = *(const float4*)(wr + 8);
      float4 w3v = *(const float4*)(wr + 12);
      const float a0k = (&av0.x)[kk];
      const float a1k = (&av1.x)[kk];
      float wv[16] = {w0v.x, w0v.y, w0v.z, w0v.w,
                      w1v.x, w1v.y, w1v.z, w1v.w,
                      w2v.x, w2v.y, w2v.z, w2v.w,
                      w3v.x, w3v.y, w3v.z, w3v.w};
      #pragma unroll
      for (int j = 0; j < 16; ++j) {
        acc[0][j] = fmaf(a0k, wv[j], acc[0][j]);
        acc[1][j] = fmaf(a1k, wv[j], acc[1][j]);
      }
    }
  }
}

// SRC: 0 = enc, 1 = h, 2 = concat(h[0..255], enc[256..285])
template <int SRC, bool RELU, int K, int N>
__device__ __forceinline__ void run_layer(const float* __restrict__ W,
                                          const float* __restrict__ Bv,
                                          Smem& sm, int tid) {
  const int tr = tid >> 4;   // 0..31
  const int tc = tid & 15;   // 0..15
  float acc[2][16];
  #pragma unroll
  for (int i = 0; i < 2; ++i)
    #pragma unroll
    for (int j = 0; j < 16; ++j) acc[i][j] = 0.f;

  constexpr int NCH = (K + KC - 1) / KC;
  #pragma unroll 1
  for (int ch = 0; ch < NCH; ++ch) {
    const int kb = ch * KC;
    __syncthreads();  // previous chunk's compute done reading wst
    // stage KC x 256 chunk (zero-fill out-of-range rows/cols)
    #pragma unroll
    for (int it = 0; it < (KC * 256) / TPB; ++it) {
      const int idx = it * TPB + tid;
      const int k = idx >> 8;
      const int c = idx & 255;
      float v = 0.f;
      if ((kb + k) < K && c < N) v = W[(size_t)(kb + k) * N + c];
      sm.wst[idx] = v;
    }
    __syncthreads();
    const int r0 = tr * 2;
    const float* a0;
    int lda;
    if (SRC == 0) {
      a0 = &sm.enc[r0 * LDE + kb]; lda = LDE;
    } else if (SRC == 1) {
      a0 = &sm.h[r0 * LDH + kb]; lda = LDH;
    } else {
      if (kb < 256) { a0 = &sm.h[r0 * LDH + kb]; lda = LDH; }
      else          { a0 = &sm.enc[r0 * LDE + (kb - 256)]; lda = LDE; }
    }
    accum_chunk(a0, a0 + lda, &sm.wst[tc * 16], acc);
  }
  __syncthreads();  // all reads of h done before overwrite
  #pragma unroll
  for (int i = 0; i < 2; ++i) {
    const int p = tr * 2 + i;
    #pragma unroll
    for (int j = 0; j < 16; ++j) {
      const int c = tc * 16 + j;
      if (c < N) {
        float v = acc[i][j] + Bv[c];
        if (RELU) v = fmaxf(v, 0.f);
        sm.h[p * LDH + c] = v;
      }
    }
  }
  __syncthreads();
}

__launch_bounds__(TPB, 1)
__global__ void nerf_fused(const float* __restrict__ x, const float* __restrict__ off,
                           const float* __restrict__ w0, const float* __restrict__ b0,
                           const float* __restrict__ w1, const float* __restrict__ b1,
                           const float* __restrict__ w2, const float* __restrict__ b2,
                           const float* __restrict__ w3, const float* __restrict__ b3,
                           const float* __restrict__ w4, const float* __restrict__ b4,
                           const float* __restrict__ w5, const float* __restrict__ b5,
                           const float* __restrict__ w6, const float* __restrict__ b6,
                           const float* __restrict__ w7, const float* __restrict__ b7,
                           const float* __restrict__ w8, const float* __restrict__ b8,
                           float* __restrict__ out) {
  __shared__ Smem sm;
  const int tid = threadIdx.x;
  const int b = blockIdx.x;

  const float ox = x[b * 6 + 0], oy = x[b * 6 + 1], oz = x[b * 6 + 2];
  const float dx = x[b * 6 + 3], dy = x[b * 6 + 4], dz = x[b * 6 + 5];
  const float norm = sqrtf(dx * dx + dy * dy + dz * dz);

  // ---- setup: enc, dist (threads 0..63; one thread per sample) ----
  if (tid < 64) {
    const int s = tid;
    if (s == 0) {
      sm.vdir[0] = dx / norm; sm.vdir[1] = dy / norm; sm.vdir[2] = dz / norm;
    }
    const float offv = off[s * BB + b];
    const float z = NEAR_ + (s + offv) * ((FAR_ - NEAR_) / SS);
    float dist;
    if (s < SS - 1) {
      const float offn = off[(s + 1) * BB + b];
      const float zn = NEAR_ + (s + 1 + offn) * ((FAR_ - NEAR_) / SS);
      dist = (zn - z) * norm;
    } else {
      dist = 1e10f;
    }
    sm.dist[s] = dist;
    const float pos[3] = {ox + dx * z, oy + dy * z, oz + dz * z};
    #pragma unroll
    for (int c = 0; c < 3; ++c) {
      #pragma unroll
      for (int l = 0; l < 5; ++l) {
        const float freq = (float)M_PI * exp2f((float)(l - 2));
        float sv, cv;
        sincosf(pos[c] * freq, &sv, &cv);
        sm.enc[s * LDE + c * 10 + l * 2 + 0] = sv;
        sm.enc[s * LDE + c * 10 + l * 2 + 1] = cv;
      }
    }
    sm.enc[s * LDE + 30] = 0.f;  // zero pads: read by b128 a-loads w/ zero weights
    sm.enc[s * LDE + 31] = 0.f;
  }
  __syncthreads();

  // ---- MLP ----
  run_layer<0, true,  30, 256>(w0, b0, sm, tid);
  run_layer<1, true, 256, 256>(w1, b1, sm, tid);
  run_layer<1, true, 256, 256>(w2, b2, sm, tid);
  run_layer<1, true, 256, 256>(w3, b3, sm, tid);
  run_layer<2, true, 286, 256>(w4, b4, sm, tid);
  run_layer<1, true, 256, 256>(w5, b5, sm, tid);
  run_layer<1, true, 256, 256>(w6, b6, sm, tid);
  run_layer<1, false, 256, 129>(w7, b7, sm, tid);  // fd: [density, feat(128)]

  // ---- color head + volume render (wave 0: one lane per sample) ----
  if (tid < 64) {
    const int p = tid;
    const float dens = sm.h[p * LDH + 0];
    float fsum[3] = {b8[0], b8[1], b8[2]};
    #pragma unroll 4
    for (int k = 0; k < 128; ++k) {
      const float f = fmaxf(sm.h[p * LDH + 1 + k], 0.f);
      fsum[0] = fmaf(f, w8[k * 3 + 0], fsum[0]);
      fsum[1] = fmaf(f, w8[k * 3 + 1], fsum[1]);
      fsum[2] = fmaf(f, w8[k * 3 + 2], fsum[2]);
    }
    #pragma unroll
    for (int c = 0; c < 3; ++c) {
      const float vd = sm.vdir[c];
      fsum[0] = fmaf(vd, w8[(128 + c) * 3 + 0], fsum[0]);
      fsum[1] = fmaf(vd, w8[(128 + c) * 3 + 1], fsum[1]);
      fsum[2] = fmaf(vd, w8[(128 + c) * 3 + 2], fsum[2]);
    }
    float col[3];
    #pragma unroll
    for (int c = 0; c < 3; ++c) col[c] = 1.f / (1.f + expf(-fsum[c]));

    const float dist = sm.dist[p];
    const float alpha = 1.f - expf(-fmaxf(dens, 0.f) * dist);
    float t = 1.f - alpha + 1e-10f;
    // inclusive cumprod across 64 lanes
    float cum = t;
    #pragma unroll
    for (int d = 1; d < 64; d <<= 1) {
      const float up = __shfl_up(cum, d, 64);
      if (p >= d) cum *= up;
    }
    const float wgt = alpha * cum;
    float oc[3] = {col[0] * wgt, col[1] * wgt, col[2] * wgt};
    #pragma unroll
    for (int d = 32; d >= 1; d >>= 1) {
      #pragma unroll
      for (int c = 0; c < 3; ++c) oc[c] += __shfl_down(oc[c], d, 64);
    }
    if (p == 0) {
      out[b * 3 + 0] = oc[0];
      out[b * 3 + 1] = oc[1];
      out[b * 3 + 2] = oc[2];
    }
  }
}

extern "C" void kernel_launch(void* const* d_in, const int* in_sizes, int n_in,
                              void* d_out, int out_size, void* d_ws, size_t ws_size,
                              hipStream_t stream) {
  (void)in_sizes; (void)n_in; (void)d_ws; (void)ws_size; (void)out_size;
  const float* x   = (const float*)d_in[0];
  const float* off = (const float*)d_in[1];
  const float* w0 = (const float*)d_in[2];  const float* b0 = (const float*)d_in[3];
  const float* w1 = (const float*)d_in[4];  const float* b1 = (const float*)d_in[5];
  const float* w2 = (const float*)d_in[6];  const float* b2 = (const float*)d_in[7];
  const float* w3 = (const float*)d_in[8];  const float* b3 = (const float*)d_in[9];
  const float* w4 = (const float*)d_in[10]; const float* b4 = (const float*)d_in[11];
  const float* w5 = (const float*)d_in[12]; const float* b5 = (const float*)d_in[13];
  const float* w6 = (const float*)d_in[14]; const float* b6 = (const float*)d_in[15];
  const float* w7 = (const float*)d_in[16]; const float* b7 = (const float*)d_in[17];
  const float* w8 = (const float*)d_in[18]; const float* b8 = (const float*)d_in[19];
  nerf_fused<<<BB, TPB, 0, stream>>>(x, off, w0, b0, w1, b1, w2, b2, w3, b3,
                                     w4, b4, w5, b5, w6, b6, w7, b7, w8, b8,
                                     (float*)d_out);
}

// Round 2
// 3654.900 us; speedup vs baseline: 2.0941x; 2.0941x over previous
//
#include <hip/hip_runtime.h>
#include <math.h>

// NerfMLP: S=64 samples/ray, B=4096 rays, H=256.
// One block per ray (64 samples = 64 GEMM rows), 512 threads (8 waves).
// Wave w owns rows w*8..w*8+7; lane l owns cols l*4..l*4+3.
//  -> weight LDS reads: stride-1 float4 across lanes (conflict-free)
//  -> activation LDS reads: wave-uniform address (broadcast, free)
// Double-buffered weight staging (KC=32 x2). Layer-7 output stored at
// stride 131 so the color head's per-sample reads spread across all banks.

#define SS 64
#define BB 4096
#define NEAR_ 2.0f
#define FAR_ 6.0f

#define TPB 512
#define KC 32
#define WSTSZ (KC * 256)   // floats per weight buffer

struct __align__(16) Smem {
  float h[64 * 256];       // activations (65536 B); layer7 reuses at stride 131
  float enc[64 * 32];      // positional encoding, cols 30,31 zeroed (8192 B)
  float wst[2 * WSTSZ];    // double-buffered weight chunks (65536 B)
  float dist[64];
  float vdir[3];
  float w8s[396];          // color-head weights
};
// total ~141 KB -> 1 block/CU, 8 waves

template <int LDA>
__device__ __forceinline__ void cchunk(const float* __restrict__ ab,
                                       const float* __restrict__ wl,
                                       float acc[8][4]) {
  #pragma unroll
  for (int k4 = 0; k4 < KC; k4 += 4) {
    const float4 w0v = *(const float4*)(wl + (k4 + 0) * 256);
    const float4 w1v = *(const float4*)(wl + (k4 + 1) * 256);
    const float4 w2v = *(const float4*)(wl + (k4 + 2) * 256);
    const float4 w3v = *(const float4*)(wl + (k4 + 3) * 256);
    #pragma unroll
    for (int i = 0; i < 8; ++i) {
      const float4 av = *(const float4*)(ab + i * LDA + k4);
      acc[i][0] = fmaf(av.x, w0v.x, acc[i][0]);
      acc[i][1] = fmaf(av.x, w0v.y, acc[i][1]);
      acc[i][2] = fmaf(av.x, w0v.z, acc[i][2]);
      acc[i][3] = fmaf(av.x, w0v.w, acc[i][3]);
      acc[i][0] = fmaf(av.y, w1v.x, acc[i][0]);
      acc[i][1] = fmaf(av.y, w1v.y, acc[i][1]);
      acc[i][2] = fmaf(av.y, w1v.z, acc[i][2]);
      acc[i][3] = fmaf(av.y, w1v.w, acc[i][3]);
      acc[i][0] = fmaf(av.z, w2v.x, acc[i][0]);
      acc[i][1] = fmaf(av.z, w2v.y, acc[i][1]);
      acc[i][2] = fmaf(av.z, w2v.z, acc[i][2]);
      acc[i][3] = fmaf(av.z, w2v.w, acc[i][3]);
      acc[i][0] = fmaf(av.w, w3v.x, acc[i][0]);
      acc[i][1] = fmaf(av.w, w3v.y, acc[i][1]);
      acc[i][2] = fmaf(av.w, w3v.z, acc[i][2]);
      acc[i][3] = fmaf(av.w, w3v.w, acc[i][3]);
    }
  }
}

template <int K, int N>
__device__ __forceinline__ void stage(const float* __restrict__ W, int kb,
                                      float* __restrict__ dst, int tid) {
  if (N == 256) {
    #pragma unroll
    for (int it = 0; it < 4; ++it) {
      const int f4 = it * TPB + tid;
      const int k = f4 >> 6;
      const int c4 = (f4 & 63) << 2;
      float4 v = make_float4(0.f, 0.f, 0.f, 0.f);
      if (kb + k < K) v = *(const float4*)(W + (size_t)(kb + k) * N + c4);
      *(float4*)(dst + k * 256 + c4) = v;
    }
  } else {
    #pragma unroll
    for (int it = 0; it < 16; ++it) {
      const int idx = it * TPB + tid;
      const int k = idx >> 8;
      const int c = idx & 255;
      float v = 0.f;
      if (kb + k < K && c < N) v = W[(size_t)(kb + k) * N + c];
      dst[idx] = v;
    }
  }
}

// SRC: 0 = enc, 1 = h, 2 = concat(h, enc). OST: output row stride in sm.h.
template <int SRC, bool RELU, int K, int N, int OST>
__device__ __attribute__((noinline)) void run_layer(const float* __restrict__ W,
                                                    const float* __restrict__ Bv,
                                                    Smem* smp, int tid) {
  Smem& sm = *smp;
  const int w = tid >> 6;      // wave 0..7 -> rows w*8..w*8+7
  const int lane = tid & 63;   // cols lane*4..lane*4+3
  float acc[8][4];
  #pragma unroll
  for (int i = 0; i < 8; ++i)
    #pragma unroll
    for (int j = 0; j < 4; ++j) acc[i][j] = 0.f;

  constexpr int NCH = (K + KC - 1) / KC;
  stage<K, N>(W, 0, &sm.wst[0], tid);
  __syncthreads();
  #pragma unroll 1
  for (int ch = 0; ch < NCH; ++ch) {
    const int kb = ch * KC;
    const int buf = ch & 1;
    if (ch + 1 < NCH) stage<K, N>(W, kb + KC, &sm.wst[(buf ^ 1) * WSTSZ], tid);
    const float* wl = &sm.wst[buf * WSTSZ] + lane * 4;
    if (SRC == 0) {
      cchunk<32>(&sm.enc[(w * 8) * 32], wl, acc);
    } else if (SRC == 1) {
      cchunk<256>(&sm.h[(w * 8) * 256 + kb], wl, acc);
    } else {
      if (kb < 256) cchunk<256>(&sm.h[(w * 8) * 256 + kb], wl, acc);
      else          cchunk<32>(&sm.enc[(w * 8) * 32], wl, acc);
    }
    __syncthreads();
  }

  // write output (all reads of h finished at the last barrier)
  if (N == 256) {
    const float4 bv = *(const float4*)(Bv + lane * 4);
    #pragma unroll
    for (int i = 0; i < 8; ++i) {
      const int row = w * 8 + i;
      float4 o;
      o.x = acc[i][0] + bv.x;
      o.y = acc[i][1] + bv.y;
      o.z = acc[i][2] + bv.z;
      o.w = acc[i][3] + bv.w;
      if (RELU) {
        o.x = fmaxf(o.x, 0.f); o.y = fmaxf(o.y, 0.f);
        o.z = fmaxf(o.z, 0.f); o.w = fmaxf(o.w, 0.f);
      }
      *(float4*)(&sm.h[row * OST + lane * 4]) = o;
    }
  } else {
    #pragma unroll
    for (int i = 0; i < 8; ++i) {
      const int row = w * 8 + i;
      #pragma unroll
      for (int j = 0; j < 4; ++j) {
        const int c = lane * 4 + j;
        if (c < N) {
          float v = acc[i][j] + Bv[c];
          if (RELU) v = fmaxf(v, 0.f);
          sm.h[row * OST + c] = v;
        }
      }
    }
  }
  __syncthreads();
}

__launch_bounds__(TPB)
__global__ void nerf_fused(const float* __restrict__ x, const float* __restrict__ off,
                           const float* __restrict__ w0, const float* __restrict__ b0,
                           const float* __restrict__ w1, const float* __restrict__ b1,
                           const float* __restrict__ w2, const float* __restrict__ b2,
                           const float* __restrict__ w3, const float* __restrict__ b3,
                           const float* __restrict__ w4, const float* __restrict__ b4,
                           const float* __restrict__ w5, const float* __restrict__ b5,
                           const float* __restrict__ w6, const float* __restrict__ b6,
                           const float* __restrict__ w7, const float* __restrict__ b7,
                           const float* __restrict__ w8, const float* __restrict__ b8,
                           float* __restrict__ out) {
  __shared__ Smem sm;
  const int tid = threadIdx.x;
  const int b = blockIdx.x;

  const float ox = x[b * 6 + 0], oy = x[b * 6 + 1], oz = x[b * 6 + 2];
  const float dx = x[b * 6 + 3], dy = x[b * 6 + 4], dz = x[b * 6 + 5];
  const float norm = sqrtf(dx * dx + dy * dy + dz * dz);

  if (tid < 396) sm.w8s[tid] = (tid < 393) ? w8[tid] : 0.f;

  // ---- setup: enc, dist (one thread per sample) ----
  if (tid < 64) {
    const int s = tid;
    if (s == 0) {
      sm.vdir[0] = dx / norm; sm.vdir[1] = dy / norm; sm.vdir[2] = dz / norm;
    }
    const float offv = off[s * BB + b];
    const float z = NEAR_ + (s + offv) * ((FAR_ - NEAR_) / SS);
    float dist;
    if (s < SS - 1) {
      const float offn = off[(s + 1) * BB + b];
      const float zn = NEAR_ + (s + 1 + offn) * ((FAR_ - NEAR_) / SS);
      dist = (zn - z) * norm;
    } else {
      dist = 1e10f;
    }
    sm.dist[s] = dist;
    const float pos[3] = {ox + dx * z, oy + dy * z, oz + dz * z};
    #pragma unroll
    for (int c = 0; c < 3; ++c) {
      #pragma unroll
      for (int l = 0; l < 5; ++l) {
        const float freq = (float)M_PI * exp2f((float)(l - 2));
        float sv, cv;
        sincosf(pos[c] * freq, &sv, &cv);
        sm.enc[s * 32 + c * 10 + l * 2 + 0] = sv;
        sm.enc[s * 32 + c * 10 + l * 2 + 1] = cv;
      }
    }
    sm.enc[s * 32 + 30] = 0.f;
    sm.enc[s * 32 + 31] = 0.f;
  }
  __syncthreads();

  // ---- MLP ----
  run_layer<0, true,  30, 256, 256>(w0, b0, &sm, tid);
  run_layer<1, true, 256, 256, 256>(w1, b1, &sm, tid);
  run_layer<1, true, 256, 256, 256>(w2, b2, &sm, tid);
  run_layer<1, true, 256, 256, 256>(w3, b3, &sm, tid);
  run_layer<2, true, 286, 256, 256>(w4, b4, &sm, tid);
  run_layer<1, true, 256, 256, 256>(w5, b5, &sm, tid);
  run_layer<1, true, 256, 256, 256>(w6, b6, &sm, tid);
  run_layer<1, false, 256, 129, 131>(w7, b7, &sm, tid);  // fd -> h at stride 131

  // ---- color head + volume render (wave 0; stride-131 reads hit all banks) ----
  if (tid < 64) {
    const int p = tid;
    const float dens = sm.h[p * 131 + 0];
    float fsum[3] = {b8[0], b8[1], b8[2]};
    #pragma unroll 4
    for (int k = 0; k < 128; ++k) {
      const float f = fmaxf(sm.h[p * 131 + 1 + k], 0.f);
      fsum[0] = fmaf(f, sm.w8s[k * 3 + 0], fsum[0]);
      fsum[1] = fmaf(f, sm.w8s[k * 3 + 1], fsum[1]);
      fsum[2] = fmaf(f, sm.w8s[k * 3 + 2], fsum[2]);
    }
    #pragma unroll
    for (int c = 0; c < 3; ++c) {
      const float vd = sm.vdir[c];
      fsum[0] = fmaf(vd, sm.w8s[(128 + c) * 3 + 0], fsum[0]);
      fsum[1] = fmaf(vd, sm.w8s[(128 + c) * 3 + 1], fsum[1]);
      fsum[2] = fmaf(vd, sm.w8s[(128 + c) * 3 + 2], fsum[2]);
    }
    float col[3];
    #pragma unroll
    for (int c = 0; c < 3; ++c) col[c] = 1.f / (1.f + expf(-fsum[c]));

    const float dist = sm.dist[p];
    const float alpha = 1.f - expf(-fmaxf(dens, 0.f) * dist);
    float cum = 1.f - alpha + 1e-10f;
    #pragma unroll
    for (int d = 1; d < 64; d <<= 1) {
      const float up = __shfl_up(cum, d, 64);
      if (p >= d) cum *= up;
    }
    const float wgt = alpha * cum;
    float oc[3] = {col[0] * wgt, col[1] * wgt, col[2] * wgt};
    #pragma unroll
    for (int d = 32; d >= 1; d >>= 1) {
      #pragma unroll
      for (int c = 0; c < 3; ++c) oc[c] += __shfl_down(oc[c], d, 64);
    }
    if (p == 0) {
      out[b * 3 + 0] = oc[0];
      out[b * 3 + 1] = oc[1];
      out[b * 3 + 2] = oc[2];
    }
  }
}

extern "C" void kernel_launch(void* const* d_in, const int* in_sizes, int n_in,
                              void* d_out, int out_size, void* d_ws, size_t ws_size,
                              hipStream_t stream) {
  (void)in_sizes; (void)n_in; (void)d_ws; (void)ws_size; (void)out_size;
  const float* x   = (const float*)d_in[0];
  const float* off = (const float*)d_in[1];
  const float* w0 = (const float*)d_in[2];  const float* b0 = (const float*)d_in[3];
  const float* w1 = (const float*)d_in[4];  const float* b1 = (const float*)d_in[5];
  const float* w2 = (const float*)d_in[6];  const float* b2 = (const float*)d_in[7];
  const float* w3 = (const float*)d_in[8];  const float* b3 = (const float*)d_in[9];
  const float* w4 = (const float*)d_in[10]; const float* b4 = (const float*)d_in[11];
  const float* w5 = (const float*)d_in[12]; const float* b5 = (const float*)d_in[13];
  const float* w6 = (const float*)d_in[14]; const float* b6 = (const float*)d_in[15];
  const float* w7 = (const float*)d_in[16]; const float* b7 = (const float*)d_in[17];
  const float* w8 = (const float*)d_in[18]; const float* b8 = (const float*)d_in[19];
  nerf_fused<<<BB, TPB, 0, stream>>>(x, off, w0, b0, w1, b1, w2, b2, w3, b3,
                                     w4, b4, w5, b5, w6, b6, w7, b7, w8, b8,
                                     (float*)d_out);
}

// Round 3
// 929.590 us; speedup vs baseline: 8.2334x; 3.9317x over previous
//
#include <hip/hip_runtime.h>
#include <math.h>

// NerfMLP via split-precision f16 MFMA (a = ah+al planes; 3 passes/tile:
// ah*bh + ah*bl + al*bh, fp32 accum -> ~2^-22 relative error).
// Prologue kernel reorders+splits all weights into MFMA B-fragment order
// in d_ws (hi plane | lo plane). Main kernel: 1 ray/block, 64 rows, 8 waves,
// wave grid 2M x 4N (32x64 tile), mfma_f32_16x16x32_f16.
// h planes XOR-swizzled (col ^ ((row&7)<<3)) -> uniform 8 lanes/bank.

#define SS 64
#define BB 4096
#define NEAR_ 2.0f
#define FAR_ 6.0f
#define TPB 512
#define PLANE 477696  // f16 elems per plane in d_ws

typedef _Float16 v8h __attribute__((ext_vector_type(8)));
typedef float v4f __attribute__((ext_vector_type(4)));
typedef unsigned int u32x4 __attribute__((ext_vector_type(4)));

// per-layer fragment-offset (f16 elems) in each plane; head at 475136
__device__ __constant__ const int kLoff[9] = {0, 8192, 73728, 139264, 204800,
                                              278528, 344064, 409600, 475136};

struct __align__(16) Smem {
  _Float16 h_hi[64 * 256];        // 32 KB  (activation hi plane, swizzled)
  _Float16 h_lo[64 * 256];        // 32 KB
  _Float16 wst[2][2][16 * 512];   // 64 KB  [buf][plane][tile*512+lane*8]
  _Float16 enc_hi[64 * 32];       // 4 KB   (cols 30,31 zero)
  _Float16 enc_lo[64 * 32];       // 4 KB
  float dist[64];
  float vdir[3];
  float rgb[64][4];
};  // ~137.4 KB -> 1 block/CU, 8 waves

__device__ __forceinline__ int hswz(int row, int col) {
  return row * 256 + (col ^ ((row & 7) << 3));
}

// ---------------- prologue: weights -> fragment-ordered f16 hi/lo ----------
struct WP { const float* p[9]; };

__launch_bounds__(TPB)
__global__ void prep_weights(WP wp, _Float16* __restrict__ ws) {
  // block = one (layer, kstep): starts per layer in block index space
  const int starts[10] = {0, 1, 9, 17, 25, 34, 42, 50, 58, 63};
  __shared__ float wtmp[32 * 256];
  const int bi = blockIdx.x;
  int layer = 0;
  #pragma unroll
  for (int i = 1; i < 9; ++i) if (bi >= starts[i]) layer = i;
  const int kstep = bi - starts[layer];
  const int ntiles = (layer == 8) ? 1 : 16;
  const int ncols = ntiles * 16;
  const int tid = threadIdx.x;
  const float* __restrict__ W = wp.p[layer];

  for (int idx = tid; idx < 32 * ncols; idx += TPB) {
    const int k = idx / ncols;
    const int nn = idx % ncols;
    const int gk = kstep * 32 + k;
    float v = 0.f;
    switch (layer) {
      case 0: if (gk < 30) v = W[gk * 256 + nn]; break;          // [30][256]
      case 4: if (gk < 286) v = W[gk * 256 + nn]; break;         // [286][256]
      case 7: if (nn < 129) v = W[gk * 129 + nn]; break;         // [256][129]
      case 8: if (gk >= 1 && gk <= 131 && nn < 3) v = W[(gk - 1) * 3 + nn]; break;
      default: v = W[gk * 256 + nn];                              // [256][256]
    }
    wtmp[k * 256 + nn] = v;
  }
  __syncthreads();

  const int nelems = ntiles * 512;
  const int base = kLoff[layer] + kstep * nelems;
  for (int e0 = tid * 16; e0 < nelems; e0 += TPB * 16) {
    _Float16 hbuf[16], lbuf[16];
    #pragma unroll
    for (int j16 = 0; j16 < 16; ++j16) {
      const int e = e0 + j16;
      const int tile = e >> 9;
      const int lanee = (e >> 3) & 63;
      const int j = e & 7;
      const int k = ((lanee >> 4) << 3) + j;       // k within 32-chunk
      const int nn = tile * 16 + (lanee & 15);     // col
      const float v = wtmp[k * 256 + nn];
      const _Float16 hi = (_Float16)v;
      hbuf[j16] = hi;
      lbuf[j16] = (_Float16)(v - (float)hi);
    }
    *(u32x4*)(ws + base + e0)           = *(const u32x4*)&hbuf[0];
    *(u32x4*)(ws + base + e0 + 8)       = *(const u32x4*)&hbuf[8];
    *(u32x4*)(ws + PLANE + base + e0)     = *(const u32x4*)&lbuf[0];
    *(u32x4*)(ws + PLANE + base + e0 + 8) = *(const u32x4*)&lbuf[8];
  }
}

// ---------------- main kernel helpers ----------------
__device__ __forceinline__ void stage_regs(const _Float16* __restrict__ ws,
                                           int off, u32x4 r[4]) {
  const int tid = threadIdx.x;
  const u32x4* ghi = (const u32x4*)(ws + off);
  const u32x4* glo = (const u32x4*)(ws + PLANE + off);
  r[0] = ghi[tid]; r[1] = ghi[tid + 512];
  r[2] = glo[tid]; r[3] = glo[tid + 512];
}
__device__ __forceinline__ void stage_write(Smem& sm, int buf, const u32x4 r[4]) {
  const int tid = threadIdx.x;
  u32x4* whi = (u32x4*)&sm.wst[buf][0][0];
  u32x4* wlo = (u32x4*)&sm.wst[buf][1][0];
  whi[tid] = r[0]; whi[tid + 512] = r[1];
  wlo[tid] = r[2]; wlo[tid + 512] = r[3];
}

// ASRC: 0 = h planes (swizzled, at kstep), 1 = enc planes (single chunk)
template <int ASRC>
__device__ __forceinline__ void step_compute(Smem& sm, int buf, int kstep,
                                             int m, int n, int lane,
                                             v4f acc[2][4]) {
  const int r = lane & 15, g = lane >> 4;
  v8h ah[2], al[2];
  #pragma unroll
  for (int i = 0; i < 2; ++i) {
    const int row = m * 32 + i * 16 + r;
    if (ASRC == 0) {
      const int idx = hswz(row, kstep * 32 + g * 8);
      ah[i] = *(const v8h*)&sm.h_hi[idx];
      al[i] = *(const v8h*)&sm.h_lo[idx];
    } else {
      const int idx = row * 32 + g * 8;
      ah[i] = *(const v8h*)&sm.enc_hi[idx];
      al[i] = *(const v8h*)&sm.enc_lo[idx];
    }
  }
  #pragma unroll
  for (int t = 0; t < 4; ++t) {
    const int tile = n * 4 + t;
    const v8h bh = *(const v8h*)&sm.wst[buf][0][tile * 512 + lane * 8];
    const v8h bl = *(const v8h*)&sm.wst[buf][1][tile * 512 + lane * 8];
    #pragma unroll
    for (int i = 0; i < 2; ++i) {
      acc[i][t] = __builtin_amdgcn_mfma_f32_16x16x32_f16(ah[i], bh, acc[i][t], 0, 0, 0);
      acc[i][t] = __builtin_amdgcn_mfma_f32_16x16x32_f16(ah[i], bl, acc[i][t], 0, 0, 0);
      acc[i][t] = __builtin_amdgcn_mfma_f32_16x16x32_f16(al[i], bh, acc[i][t], 0, 0, 0);
    }
  }
}

// MODE: 0 = enc only (NS=1), 1 = h only (NS=8), 2 = h steps 0-7 + enc step 8
template <int MODE, int NREAL>
__device__ void run_layer(const _Float16* __restrict__ ws, int loff,
                          const float* __restrict__ Bv, Smem& sm) {
  const int tid = threadIdx.x;
  const int w = tid >> 6, lane = tid & 63;
  const int m = w >> 2, n = w & 3;
  constexpr int NS = (MODE == 0) ? 1 : (MODE == 1 ? 8 : 9);
  v4f acc[2][4];
  #pragma unroll
  for (int i = 0; i < 2; ++i)
    #pragma unroll
    for (int t = 0; t < 4; ++t) acc[i][t] = (v4f){0.f, 0.f, 0.f, 0.f};

  u32x4 sreg[4];
  stage_regs(ws, loff, sreg);
  stage_write(sm, 0, sreg);
  __syncthreads();
  int buf = 0;
  #pragma unroll 1
  for (int s = 0; s < NS; ++s) {
    if (s + 1 < NS) stage_regs(ws, loff + (s + 1) * 8192, sreg);
    if (MODE == 0)      step_compute<1>(sm, buf, 0, m, n, lane, acc);
    else if (MODE == 1) step_compute<0>(sm, buf, s, m, n, lane, acc);
    else {
      if (s < 8) step_compute<0>(sm, buf, s, m, n, lane, acc);
      else       step_compute<1>(sm, buf, 0, m, n, lane, acc);
    }
    if (s + 1 < NS) stage_write(sm, buf ^ 1, sreg);
    __syncthreads();
    buf ^= 1;
  }

  // epilogue: bias + relu + split to f16 hi/lo planes (in-place safe: all
  // reads of h finished at the final step barrier above)
  const int r = lane & 15, g = lane >> 4;
  #pragma unroll
  for (int t = 0; t < 4; ++t) {
    const int col = (n * 4 + t) * 16 + r;
    const float bias = (col < NREAL) ? Bv[col] : 0.f;
    #pragma unroll
    for (int i = 0; i < 2; ++i) {
      #pragma unroll
      for (int q = 0; q < 4; ++q) {
        const int row = m * 32 + i * 16 + g * 4 + q;
        float v = acc[i][t][q] + bias;
        v = fmaxf(v, 0.f);
        const _Float16 hi = (_Float16)v;
        const _Float16 lo = (_Float16)(v - (float)hi);
        const int idx = hswz(row, col);
        sm.h_hi[idx] = hi;
        sm.h_lo[idx] = lo;
      }
    }
  }
  __syncthreads();
}

__launch_bounds__(TPB, 2)
__global__ void nerf_mfma(const float* __restrict__ x, const float* __restrict__ off,
                          const float* __restrict__ b0, const float* __restrict__ b1,
                          const float* __restrict__ b2, const float* __restrict__ b3,
                          const float* __restrict__ b4, const float* __restrict__ b5,
                          const float* __restrict__ b6, const float* __restrict__ b7,
                          const float* __restrict__ b8,
                          const _Float16* __restrict__ ws, float* __restrict__ out) {
  __shared__ Smem sm;
  const int tid = threadIdx.x;
  const int b = blockIdx.x;

  const float ox = x[b * 6 + 0], oy = x[b * 6 + 1], oz = x[b * 6 + 2];
  const float dx = x[b * 6 + 3], dy = x[b * 6 + 4], dz = x[b * 6 + 5];
  const float norm = sqrtf(dx * dx + dy * dy + dz * dz);

  // setup: enc (split planes), dist, vdir
  if (tid < 64) {
    const int s = tid;
    if (s == 0) {
      sm.vdir[0] = dx / norm; sm.vdir[1] = dy / norm; sm.vdir[2] = dz / norm;
    }
    const float offv = off[s * BB + b];
    const float z = NEAR_ + (s + offv) * ((FAR_ - NEAR_) / SS);
    float dist;
    if (s < SS - 1) {
      const float offn = off[(s + 1) * BB + b];
      const float zn = NEAR_ + (s + 1 + offn) * ((FAR_ - NEAR_) / SS);
      dist = (zn - z) * norm;
    } else {
      dist = 1e10f;
    }
    sm.dist[s] = dist;
    const float pos[3] = {ox + dx * z, oy + dy * z, oz + dz * z};
    #pragma unroll
    for (int c = 0; c < 3; ++c) {
      #pragma unroll
      for (int l = 0; l < 5; ++l) {
        const float freq = (float)M_PI * exp2f((float)(l - 2));
        float sv, cv;
        sincosf(pos[c] * freq, &sv, &cv);
        const int i0 = s * 32 + c * 10 + l * 2;
        const _Float16 sh = (_Float16)sv;
        const _Float16 ch = (_Float16)cv;
        sm.enc_hi[i0 + 0] = sh; sm.enc_lo[i0 + 0] = (_Float16)(sv - (float)sh);
        sm.enc_hi[i0 + 1] = ch; sm.enc_lo[i0 + 1] = (_Float16)(cv - (float)ch);
      }
    }
    sm.enc_hi[s * 32 + 30] = (_Float16)0.f; sm.enc_lo[s * 32 + 30] = (_Float16)0.f;
    sm.enc_hi[s * 32 + 31] = (_Float16)0.f; sm.enc_lo[s * 32 + 31] = (_Float16)0.f;
  }
  // (no explicit barrier needed: run_layer's staging barrier covers it)

  run_layer<0, 256>(ws, 0,      b0, sm);
  run_layer<1, 256>(ws, 8192,   b1, sm);
  run_layer<1, 256>(ws, 73728,  b2, sm);
  run_layer<1, 256>(ws, 139264, b3, sm);
  run_layer<2, 256>(ws, 204800, b4, sm);
  run_layer<1, 256>(ws, 278528, b5, sm);
  run_layer<1, 256>(ws, 344064, b6, sm);
  run_layer<1, 129>(ws, 409600, b7, sm);  // fd: [relu(density), relu(feat)...,0]

  // overwrite cols 129..131 with raw viewdir (split)
  if (tid < 64) {
    #pragma unroll
    for (int c = 0; c < 3; ++c) {
      const float v = sm.vdir[c];
      const _Float16 hi = (_Float16)v;
      const _Float16 lo = (_Float16)(v - (float)hi);
      const int idx = hswz(tid, 129 + c);
      sm.h_hi[idx] = hi; sm.h_lo[idx] = lo;
    }
  }
  __syncthreads();

  // color head: K=160 (cols 0..131 live, w8 frag rows 0 and >=132 zeroed in
  // prologue), N-tile 0 cols 0..2 valid. Waves 0..3, one 16-row M-tile each.
  const int w = tid >> 6, lane = tid & 63;
  if (w < 4) {
    const int r = lane & 15, g = lane >> 4;
    v4f hacc = (v4f){0.f, 0.f, 0.f, 0.f};
    #pragma unroll
    for (int s = 0; s < 5; ++s) {
      const int row = w * 16 + r;
      const int idx = hswz(row, s * 32 + g * 8);
      const v8h ah = *(const v8h*)&sm.h_hi[idx];
      const v8h al = *(const v8h*)&sm.h_lo[idx];
      const _Float16* gh = ws + 475136 + s * 512 + lane * 8;
      const v8h bh = *(const v8h*)gh;
      const v8h bl = *(const v8h*)(gh + PLANE);
      hacc = __builtin_amdgcn_mfma_f32_16x16x32_f16(ah, bh, hacc, 0, 0, 0);
      hacc = __builtin_amdgcn_mfma_f32_16x16x32_f16(ah, bl, hacc, 0, 0, 0);
      hacc = __builtin_amdgcn_mfma_f32_16x16x32_f16(al, bh, hacc, 0, 0, 0);
    }
    if (r < 3) {
      const float bias = b8[r];
      #pragma unroll
      for (int q = 0; q < 4; ++q) {
        const int row = w * 16 + g * 4 + q;
        const float logit = hacc[q] + bias;
        sm.rgb[row][r] = 1.f / (1.f + expf(-logit));
      }
    }
  }
  __syncthreads();

  // volume render (wave 0, one lane per sample)
  if (tid < 64) {
    const int p = tid;
    const int didx = hswz(p, 0);
    float dens = (float)sm.h_hi[didx] + (float)sm.h_lo[didx];
    dens = fmaxf(dens, 0.f);
    const float alpha = 1.f - expf(-dens * sm.dist[p]);
    float cum = 1.f - alpha + 1e-10f;
    #pragma unroll
    for (int d = 1; d < 64; d <<= 1) {
      const float up = __shfl_up(cum, d, 64);
      if (p >= d) cum *= up;
    }
    const float wgt = alpha * cum;
    float oc[3] = {sm.rgb[p][0] * wgt, sm.rgb[p][1] * wgt, sm.rgb[p][2] * wgt};
    #pragma unroll
    for (int d = 32; d >= 1; d >>= 1) {
      #pragma unroll
      for (int c = 0; c < 3; ++c) oc[c] += __shfl_down(oc[c], d, 64);
    }
    if (p == 0) {
      out[b * 3 + 0] = oc[0];
      out[b * 3 + 1] = oc[1];
      out[b * 3 + 2] = oc[2];
    }
  }
}

extern "C" void kernel_launch(void* const* d_in, const int* in_sizes, int n_in,
                              void* d_out, int out_size, void* d_ws, size_t ws_size,
                              hipStream_t stream) {
  (void)in_sizes; (void)n_in; (void)out_size; (void)ws_size;
  const float* x   = (const float*)d_in[0];
  const float* off = (const float*)d_in[1];
  WP wp;
  wp.p[0] = (const float*)d_in[2];   // w0
  wp.p[1] = (const float*)d_in[4];   // w1
  wp.p[2] = (const float*)d_in[6];   // w2
  wp.p[3] = (const float*)d_in[8];   // w3
  wp.p[4] = (const float*)d_in[10];  // w4
  wp.p[5] = (const float*)d_in[12];  // w5
  wp.p[6] = (const float*)d_in[14];  // w6
  wp.p[7] = (const float*)d_in[16];  // w7
  wp.p[8] = (const float*)d_in[18];  // w8
  const float* b0 = (const float*)d_in[3];
  const float* b1 = (const float*)d_in[5];
  const float* b2 = (const float*)d_in[7];
  const float* b3 = (const float*)d_in[9];
  const float* b4 = (const float*)d_in[11];
  const float* b5 = (const float*)d_in[13];
  const float* b6 = (const float*)d_in[15];
  const float* b7 = (const float*)d_in[17];
  const float* b8 = (const float*)d_in[19];
  _Float16* ws = (_Float16*)d_ws;

  prep_weights<<<63, TPB, 0, stream>>>(wp, ws);
  nerf_mfma<<<BB, TPB, 0, stream>>>(x, off, b0, b1, b2, b3, b4, b5, b6, b7, b8,
                                    ws, (float*)d_out);
}

// Round 4
// 561.406 us; speedup vs baseline: 13.6331x; 1.6558x over previous
//
#include <hip/hip_runtime.h>
#include <math.h>

// NerfMLP via split-precision f16 MFMA (3 passes: ah*bh + ah*bl + al*bh).
// R4: B-fragments load straight from global (L2-resident weights) -> no LDS
// staging, no K-loop barriers. Wave grid 1M x 8N: wave w owns cols w*32..+31
// (2 N-tiles), all 64 rows (4 M-tiles); B loads disjoint across waves.
// LDS = h/enc planes only (~73 KB) -> 2 blocks/CU.

#define SS 64
#define BB 4096
#define NEAR_ 2.0f
#define FAR_ 6.0f
#define TPB 512
#define PLANE 477696  // f16 elems per plane in d_ws

typedef _Float16 v8h __attribute__((ext_vector_type(8)));
typedef float v4f __attribute__((ext_vector_type(4)));
typedef unsigned int u32x4 __attribute__((ext_vector_type(4)));

__device__ __constant__ const int kLoff[9] = {0, 8192, 73728, 139264, 204800,
                                              278528, 344064, 409600, 475136};

struct __align__(16) Smem {
  _Float16 h_hi[64 * 256];   // 32 KB (swizzled)
  _Float16 h_lo[64 * 256];   // 32 KB
  _Float16 enc_hi[64 * 32];  // 4 KB (cols 30,31 zero)
  _Float16 enc_lo[64 * 32];  // 4 KB
  float dist[64];
  float vdir[3];
  float rgb[64][4];
};  // ~73.3 KB -> 2 blocks/CU

__device__ __forceinline__ int hswz(int row, int col) {
  return row * 256 + (col ^ ((row & 7) << 3));
}

// ---------------- prologue: weights -> fragment-ordered f16 hi/lo ----------
// (verbatim from R3 — verified layout)
struct WP { const float* p[9]; };

__launch_bounds__(TPB)
__global__ void prep_weights(WP wp, _Float16* __restrict__ ws) {
  const int starts[10] = {0, 1, 9, 17, 25, 34, 42, 50, 58, 63};
  __shared__ float wtmp[32 * 256];
  const int bi = blockIdx.x;
  int layer = 0;
  #pragma unroll
  for (int i = 1; i < 9; ++i) if (bi >= starts[i]) layer = i;
  const int kstep = bi - starts[layer];
  const int ntiles = (layer == 8) ? 1 : 16;
  const int ncols = ntiles * 16;
  const int tid = threadIdx.x;
  const float* __restrict__ W = wp.p[layer];

  for (int idx = tid; idx < 32 * ncols; idx += TPB) {
    const int k = idx / ncols;
    const int nn = idx % ncols;
    const int gk = kstep * 32 + k;
    float v = 0.f;
    switch (layer) {
      case 0: if (gk < 30) v = W[gk * 256 + nn]; break;
      case 4: if (gk < 286) v = W[gk * 256 + nn]; break;
      case 7: if (nn < 129) v = W[gk * 129 + nn]; break;
      case 8: if (gk >= 1 && gk <= 131 && nn < 3) v = W[(gk - 1) * 3 + nn]; break;
      default: v = W[gk * 256 + nn];
    }
    wtmp[k * 256 + nn] = v;
  }
  __syncthreads();

  const int nelems = ntiles * 512;
  const int base = kLoff[layer] + kstep * nelems;
  for (int e0 = tid * 16; e0 < nelems; e0 += TPB * 16) {
    _Float16 hbuf[16], lbuf[16];
    #pragma unroll
    for (int j16 = 0; j16 < 16; ++j16) {
      const int e = e0 + j16;
      const int tile = e >> 9;
      const int lanee = (e >> 3) & 63;
      const int j = e & 7;
      const int k = ((lanee >> 4) << 3) + j;
      const int nn = tile * 16 + (lanee & 15);
      const float v = wtmp[k * 256 + nn];
      const _Float16 hi = (_Float16)v;
      hbuf[j16] = hi;
      lbuf[j16] = (_Float16)(v - (float)hi);
    }
    *(u32x4*)(ws + base + e0)             = *(const u32x4*)&hbuf[0];
    *(u32x4*)(ws + base + e0 + 8)         = *(const u32x4*)&hbuf[8];
    *(u32x4*)(ws + PLANE + base + e0)     = *(const u32x4*)&lbuf[0];
    *(u32x4*)(ws + PLANE + base + e0 + 8) = *(const u32x4*)&lbuf[8];
  }
}

// ---------------- main layer: B from global, A from LDS --------------------
// MODE: 0 = enc only (NS=1), 1 = h only (NS=8), 2 = h steps 0-7 + enc step 8
template <int MODE, int NREAL>
__device__ void run_layer(const _Float16* __restrict__ ws, int loff,
                          const float* __restrict__ Bv, Smem& sm) {
  const int tid = threadIdx.x;
  const int w = tid >> 6, lane = tid & 63;
  const int r = lane & 15, g = lane >> 4;
  constexpr int NS = (MODE == 0) ? 1 : (MODE == 1 ? 8 : 9);
  v4f acc[4][2];
  #pragma unroll
  for (int mt = 0; mt < 4; ++mt)
    #pragma unroll
    for (int t = 0; t < 2; ++t) acc[mt][t] = (v4f){0.f, 0.f, 0.f, 0.f};

  #pragma unroll 2
  for (int s = 0; s < NS; ++s) {
    const _Float16* gp = ws + loff + s * 8192 + (w * 2) * 512 + lane * 8;
    const v8h bh0 = *(const v8h*)gp;
    const v8h bl0 = *(const v8h*)(gp + PLANE);
    const v8h bh1 = *(const v8h*)(gp + 512);
    const v8h bl1 = *(const v8h*)(gp + 512 + PLANE);
    v8h ah[4], al[4];
    const bool use_enc = (MODE == 0) || (MODE == 2 && s == 8);
    #pragma unroll
    for (int mt = 0; mt < 4; ++mt) {
      const int row = mt * 16 + r;
      if (use_enc) {
        const int idx = row * 32 + g * 8;
        ah[mt] = *(const v8h*)&sm.enc_hi[idx];
        al[mt] = *(const v8h*)&sm.enc_lo[idx];
      } else {
        const int idx = hswz(row, s * 32 + g * 8);
        ah[mt] = *(const v8h*)&sm.h_hi[idx];
        al[mt] = *(const v8h*)&sm.h_lo[idx];
      }
    }
    #pragma unroll
    for (int mt = 0; mt < 4; ++mt) {
      acc[mt][0] = __builtin_amdgcn_mfma_f32_16x16x32_f16(ah[mt], bh0, acc[mt][0], 0, 0, 0);
      acc[mt][0] = __builtin_amdgcn_mfma_f32_16x16x32_f16(ah[mt], bl0, acc[mt][0], 0, 0, 0);
      acc[mt][0] = __builtin_amdgcn_mfma_f32_16x16x32_f16(al[mt], bh0, acc[mt][0], 0, 0, 0);
      acc[mt][1] = __builtin_amdgcn_mfma_f32_16x16x32_f16(ah[mt], bh1, acc[mt][1], 0, 0, 0);
      acc[mt][1] = __builtin_amdgcn_mfma_f32_16x16x32_f16(ah[mt], bl1, acc[mt][1], 0, 0, 0);
      acc[mt][1] = __builtin_amdgcn_mfma_f32_16x16x32_f16(al[mt], bh1, acc[mt][1], 0, 0, 0);
    }
  }
  __syncthreads();  // all reads of h done before overwrite

  #pragma unroll
  for (int t = 0; t < 2; ++t) {
    const int col = (w * 2 + t) * 16 + r;
    const float bias = (col < NREAL) ? Bv[col] : 0.f;
    #pragma unroll
    for (int mt = 0; mt < 4; ++mt) {
      #pragma unroll
      for (int q = 0; q < 4; ++q) {
        const int row = mt * 16 + g * 4 + q;
        float v = acc[mt][t][q] + bias;
        v = fmaxf(v, 0.f);
        const _Float16 hi = (_Float16)v;
        const _Float16 lo = (_Float16)(v - (float)hi);
        const int idx = hswz(row, col);
        sm.h_hi[idx] = hi;
        sm.h_lo[idx] = lo;
      }
    }
  }
  __syncthreads();
}

__launch_bounds__(TPB, 4)
__global__ void nerf_mfma(const float* __restrict__ x, const float* __restrict__ off,
                          const float* __restrict__ b0, const float* __restrict__ b1,
                          const float* __restrict__ b2, const float* __restrict__ b3,
                          const float* __restrict__ b4, const float* __restrict__ b5,
                          const float* __restrict__ b6, const float* __restrict__ b7,
                          const float* __restrict__ b8,
                          const _Float16* __restrict__ ws, float* __restrict__ out) {
  __shared__ Smem sm;
  const int tid = threadIdx.x;
  const int b = blockIdx.x;

  const float ox = x[b * 6 + 0], oy = x[b * 6 + 1], oz = x[b * 6 + 2];
  const float dx = x[b * 6 + 3], dy = x[b * 6 + 4], dz = x[b * 6 + 5];
  const float norm = sqrtf(dx * dx + dy * dy + dz * dz);

  // setup: enc (split planes), dist, vdir
  if (tid < 64) {
    const int s = tid;
    if (s == 0) {
      sm.vdir[0] = dx / norm; sm.vdir[1] = dy / norm; sm.vdir[2] = dz / norm;
    }
    const float offv = off[s * BB + b];
    const float z = NEAR_ + (s + offv) * ((FAR_ - NEAR_) / SS);
    float dist;
    if (s < SS - 1) {
      const float offn = off[(s + 1) * BB + b];
      const float zn = NEAR_ + (s + 1 + offn) * ((FAR_ - NEAR_) / SS);
      dist = (zn - z) * norm;
    } else {
      dist = 1e10f;
    }
    sm.dist[s] = dist;
    const float pos[3] = {ox + dx * z, oy + dy * z, oz + dz * z};
    #pragma unroll
    for (int c = 0; c < 3; ++c) {
      #pragma unroll
      for (int l = 0; l < 5; ++l) {
        const float freq = (float)M_PI * exp2f((float)(l - 2));
        float sv, cv;
        sincosf(pos[c] * freq, &sv, &cv);
        const int i0 = s * 32 + c * 10 + l * 2;
        const _Float16 sh = (_Float16)sv;
        const _Float16 ch = (_Float16)cv;
        sm.enc_hi[i0 + 0] = sh; sm.enc_lo[i0 + 0] = (_Float16)(sv - (float)sh);
        sm.enc_hi[i0 + 1] = ch; sm.enc_lo[i0 + 1] = (_Float16)(cv - (float)ch);
      }
    }
    sm.enc_hi[s * 32 + 30] = (_Float16)0.f; sm.enc_lo[s * 32 + 30] = (_Float16)0.f;
    sm.enc_hi[s * 32 + 31] = (_Float16)0.f; sm.enc_lo[s * 32 + 31] = (_Float16)0.f;
  }
  __syncthreads();  // K-loop reads enc immediately (no staging barrier anymore)

  run_layer<0, 256>(ws, 0,      b0, sm);
  run_layer<1, 256>(ws, 8192,   b1, sm);
  run_layer<1, 256>(ws, 73728,  b2, sm);
  run_layer<1, 256>(ws, 139264, b3, sm);
  run_layer<2, 256>(ws, 204800, b4, sm);
  run_layer<1, 256>(ws, 278528, b5, sm);
  run_layer<1, 256>(ws, 344064, b6, sm);
  run_layer<1, 129>(ws, 409600, b7, sm);  // fd: [relu(density), relu(feat)..., 0]

  // overwrite cols 129..131 with raw viewdir (split)
  if (tid < 64) {
    #pragma unroll
    for (int c = 0; c < 3; ++c) {
      const float v = sm.vdir[c];
      const _Float16 hi = (_Float16)v;
      const _Float16 lo = (_Float16)(v - (float)hi);
      const int idx = hswz(tid, 129 + c);
      sm.h_hi[idx] = hi; sm.h_lo[idx] = lo;
    }
  }
  __syncthreads();

  // color head: K=160 (w8 frag rows 0 and >=132 zeroed in prologue).
  // Waves 0..3, one 16-row M-tile each; B direct from global.
  const int w = tid >> 6, lane = tid & 63;
  if (w < 4) {
    const int r = lane & 15, g = lane >> 4;
    v4f hacc = (v4f){0.f, 0.f, 0.f, 0.f};
    #pragma unroll
    for (int s = 0; s < 5; ++s) {
      const int row = w * 16 + r;
      const int idx = hswz(row, s * 32 + g * 8);
      const v8h ah = *(const v8h*)&sm.h_hi[idx];
      const v8h al = *(const v8h*)&sm.h_lo[idx];
      const _Float16* gh = ws + 475136 + s * 512 + lane * 8;
      const v8h bh = *(const v8h*)gh;
      const v8h bl = *(const v8h*)(gh + PLANE);
      hacc = __builtin_amdgcn_mfma_f32_16x16x32_f16(ah, bh, hacc, 0, 0, 0);
      hacc = __builtin_amdgcn_mfma_f32_16x16x32_f16(ah, bl, hacc, 0, 0, 0);
      hacc = __builtin_amdgcn_mfma_f32_16x16x32_f16(al, bh, hacc, 0, 0, 0);
    }
    if (r < 3) {
      const float bias = b8[r];
      #pragma unroll
      for (int q = 0; q < 4; ++q) {
        const int row = w * 16 + g * 4 + q;
        const float logit = hacc[q] + bias;
        sm.rgb[row][r] = 1.f / (1.f + expf(-logit));
      }
    }
  }
  __syncthreads();

  // volume render (wave 0, one lane per sample)
  if (tid < 64) {
    const int p = tid;
    const int didx = hswz(p, 0);
    float dens = (float)sm.h_hi[didx] + (float)sm.h_lo[didx];
    dens = fmaxf(dens, 0.f);
    const float alpha = 1.f - expf(-dens * sm.dist[p]);
    float cum = 1.f - alpha + 1e-10f;
    #pragma unroll
    for (int d = 1; d < 64; d <<= 1) {
      const float up = __shfl_up(cum, d, 64);
      if (p >= d) cum *= up;
    }
    const float wgt = alpha * cum;
    float oc[3] = {sm.rgb[p][0] * wgt, sm.rgb[p][1] * wgt, sm.rgb[p][2] * wgt};
    #pragma unroll
    for (int d = 32; d >= 1; d >>= 1) {
      #pragma unroll
      for (int c = 0; c < 3; ++c) oc[c] += __shfl_down(oc[c], d, 64);
    }
    if (p == 0) {
      out[b * 3 + 0] = oc[0];
      out[b * 3 + 1] = oc[1];
      out[b * 3 + 2] = oc[2];
    }
  }
}

extern "C" void kernel_launch(void* const* d_in, const int* in_sizes, int n_in,
                              void* d_out, int out_size, void* d_ws, size_t ws_size,
                              hipStream_t stream) {
  (void)in_sizes; (void)n_in; (void)out_size; (void)ws_size;
  const float* x   = (const float*)d_in[0];
  const float* off = (const float*)d_in[1];
  WP wp;
  wp.p[0] = (const float*)d_in[2];
  wp.p[1] = (const float*)d_in[4];
  wp.p[2] = (const float*)d_in[6];
  wp.p[3] = (const float*)d_in[8];
  wp.p[4] = (const float*)d_in[10];
  wp.p[5] = (const float*)d_in[12];
  wp.p[6] = (const float*)d_in[14];
  wp.p[7] = (const float*)d_in[16];
  wp.p[8] = (const float*)d_in[18];
  const float* b0 = (const float*)d_in[3];
  const float* b1 = (const float*)d_in[5];
  const float* b2 = (const float*)d_in[7];
  const float* b3 = (const float*)d_in[9];
  const float* b4 = (const float*)d_in[11];
  const float* b5 = (const float*)d_in[13];
  const float* b6 = (const float*)d_in[15];
  const float* b7 = (const float*)d_in[17];
  const float* b8 = (const float*)d_in[19];
  _Float16* ws = (_Float16*)d_ws;

  prep_weights<<<63, TPB, 0, stream>>>(wp, ws);
  nerf_mfma<<<BB, TPB, 0, stream>>>(x, off, b0, b1, b2, b3, b4, b5, b6, b7, b8,
                                    ws, (float*)d_out);
}